// Round 1
// baseline (227.292 us; speedup 1.0000x reference)
//
#include <hip/hip_runtime.h>
#include <stdint.h>

typedef __attribute__((ext_vector_type(8))) short  bf16x8;
typedef __attribute__((ext_vector_type(4))) short  short4v;
typedef __attribute__((ext_vector_type(4))) float  f32x4;
typedef __attribute__((ext_vector_type(4))) float  float4v;

__device__ __forceinline__ short f2bf(float f) {
  union { float f; uint32_t u; } c; c.f = f;
  uint32_t u = c.u;
  uint32_t r = (u + 0x7FFFu + ((u >> 16) & 1u)) >> 16;
  return (short)(uint16_t)r;
}

__device__ __forceinline__ void gload_lds16(const void* g, void* l) {
  __builtin_amdgcn_global_load_lds(
      (const __attribute__((address_space(1))) void*)g,
      (__attribute__((address_space(3))) void*)l, 16, 0, 0);
}

// ---------------- f32 -> bf16 (vectorized, 4 elems/thread) ----------------
__global__ __launch_bounds__(256) void k_f32_to_bf16(
    const float* __restrict__ in, short* __restrict__ out, int n4) {
  int i = blockIdx.x * 256 + threadIdx.x;
  if (i >= n4) return;
  float4v v = *(const float4v*)(in + (size_t)i * 4);
  short4v o;
  o.x = f2bf(v.x); o.y = f2bf(v.y); o.z = f2bf(v.z); o.w = f2bf(v.w);
  *(short4v*)(out + (size_t)i * 4) = o;
}

// ------------- transpose f32[R][C] -> bf16[C][R] (64x64 LDS tiles) -------------
__global__ __launch_bounds__(256) void k_transpose_bf16(
    const float* __restrict__ in, short* __restrict__ out, int R, int C) {
  __shared__ short tile[64][65];
  int bc = blockIdx.x * 64, br = blockIdx.y * 64;
  int tc = threadIdx.x & 63, tr = threadIdx.x >> 6;  // tr 0..3
#pragma unroll
  for (int i = 0; i < 64; i += 4)
    tile[tc][tr + i] = f2bf(in[(size_t)(br + tr + i) * C + bc + tc]);
  __syncthreads();
#pragma unroll
  for (int i = 0; i < 64; i += 4)
    out[(size_t)(bc + tr + i) * R + br + tc] = tile[tr + i][tc];
}

// ------------- GEMM: C[M][N] = A[M][K](bf16) * BT[N][K]^T + bias ---------------
// m97 structure: 128x128 tile, BK=32, 4 waves (2x2), 4x4 16x16x32 frags/wave.
template <bool F32OUT>
__global__ __launch_bounds__(256) void k_gemm_bt(
    const short* __restrict__ A, const short* __restrict__ BT,
    const float* __restrict__ bias, void* __restrict__ Cout,
    int M, int N, int K) {
  __shared__ short As[128][32];
  __shared__ short Bs[128][32];
  const int tid = threadIdx.x;
  const int w = tid >> 6, l = tid & 63;
  const int fr = l & 15, fg = l >> 4;
  const int nbn = N >> 7;
  const int bm = blockIdx.x / nbn, bn = blockIdx.x % nbn;
  const size_t brow = (size_t)bm << 7;
  const int bcol = bn << 7;
  const int wr = w >> 1, wc = w & 1;

  const int lrow = l >> 2;        // 0..15 row within 16-row chunk
  const int lk = (l & 3) << 3;    // k-part 0,8,16,24

  const short* Arow0 = A + (brow + (size_t)(w * 32 + lrow)) * K + lk;
  const short* Arow1 = Arow0 + (size_t)16 * K;
  const short* Brow0 = BT + ((size_t)(bcol + w * 32 + lrow)) * K + lk;
  const short* Brow1 = Brow0 + (size_t)16 * K;
  char* asd0 = (char*)&As[0][0] + (w * 2) * 1024;
  char* asd1 = asd0 + 1024;
  char* bsd0 = (char*)&Bs[0][0] + (w * 2) * 1024;
  char* bsd1 = bsd0 + 1024;

  f32x4 acc[4][4] = {};

  for (int kt = 0; kt < K; kt += 32) {
    gload_lds16(Arow0 + kt, asd0);
    gload_lds16(Arow1 + kt, asd1);
    gload_lds16(Brow0 + kt, bsd0);
    gload_lds16(Brow1 + kt, bsd1);
    __syncthreads();
    bf16x8 af[4], bfv[4];
#pragma unroll
    for (int m = 0; m < 4; ++m)
      af[m] = *(const bf16x8*)&As[wr * 64 + m * 16 + fr][fg * 8];
#pragma unroll
    for (int n = 0; n < 4; ++n)
      bfv[n] = *(const bf16x8*)&Bs[wc * 64 + n * 16 + fr][fg * 8];
#pragma unroll
    for (int m = 0; m < 4; ++m)
#pragma unroll
      for (int n = 0; n < 4; ++n)
        acc[m][n] = __builtin_amdgcn_mfma_f32_16x16x32_bf16(
            af[m], bfv[n], acc[m][n], 0, 0, 0);
    __syncthreads();
  }

#pragma unroll
  for (int n = 0; n < 4; ++n) {
    int col = bcol + wc * 64 + n * 16 + fr;
    float bv = bias[col];
#pragma unroll
    for (int m = 0; m < 4; ++m) {
      size_t row = brow + (size_t)(wr * 64 + m * 16 + fg * 4);
#pragma unroll
      for (int r = 0; r < 4; ++r) {
        float v = acc[m][n][r] + bv;
        if (F32OUT)
          ((float*)Cout)[(row + r) * (size_t)N + col] = v;
        else
          ((short*)Cout)[(row + r) * (size_t)N + col] = f2bf(v);
      }
    }
  }
}

// ---------------- fused anti-causal flash attention (keep k >= q) ----------------
// qkv bf16 [B*S][3072]; head h: Q cols h*64, K cols 1024+h*64, V cols 2048+h*64.
// Block: one (b,h,q-tile of 64). 4 waves x 16 q-rows. Swapped QK^T (mfma(K,Q)).
__global__ __launch_bounds__(256) void k_attn(
    const short* __restrict__ qkv, short* __restrict__ outc, int Bn, int S) {
  __shared__ short Ks[64][64];      // XOR-swizzled 16B slots within 128B rows
  __shared__ short Vt[64][72];      // V^T, padded pitch (144B rows, 16B-aligned)
  __shared__ short Pl[4][16][72];   // per-wave P [16 q][64 k], padded pitch

  const int tid = threadIdx.x;
  const int w = tid >> 6, l = tid & 63;
  const int fr = l & 15, fg = l >> 4;

  const int tq = blockIdx.x & 15;
  const int h = (blockIdx.x >> 4) & 15;
  const int b = blockIdx.x >> 8;
  const int q0 = tq << 6;

  const size_t rowbase = (size_t)b * S;
  const int qcol = q0 + w * 16 + fr;  // q index this lane holds in S^T cols

  bf16x8 qf[2];
  {
    const short* qp = qkv + (rowbase + qcol) * 3072 + h * 64 + fg * 8;
    qf[0] = *(const bf16x8*)qp;
    qf[1] = *(const bf16x8*)(qp + 32);
  }

  f32x4 o[4] = {};
  float mrow = -3.0e38f, lsum = 0.0f;

  const short* Kbase = qkv + rowbase * 3072 + 1024 + h * 64;
  const short* Vbase = qkv + rowbase * 3072 + 2048 + h * 64;

  const int NT = S >> 6;
  for (int kt = tq; kt < NT; ++kt) {
    const int k0 = kt << 6;
    // stage K via global_load_lds, source pre-swizzled so LDS slot = d-octet ^ (row&7)
    {
      int r8 = l >> 3;    // 0..7
      int slot = l & 7;   // 16B slot within row
#pragma unroll
      for (int j = 0; j < 2; ++j) {
        int ch = w * 2 + j;
        int row = ch * 8 + r8;
        int d = ((slot ^ (row & 7)) << 3);
        gload_lds16(Kbase + (size_t)(k0 + row) * 3072 + d,
                    (char*)&Ks[0][0] + ch * 1024);
      }
    }
    // stage V transposed (reg 4x4 transpose)
    {
      int kb = (tid & 15) << 2;
      int db = (tid >> 4) << 2;
      const short* vp = Vbase + (size_t)(k0 + kb) * 3072 + db;
      short4v r0 = *(const short4v*)(vp);
      short4v r1 = *(const short4v*)(vp + 3072);
      short4v r2 = *(const short4v*)(vp + 2 * 3072);
      short4v r3 = *(const short4v*)(vp + 3 * 3072);
      short4v c0 = {r0.x, r1.x, r2.x, r3.x};
      short4v c1 = {r0.y, r1.y, r2.y, r3.y};
      short4v c2 = {r0.z, r1.z, r2.z, r3.z};
      short4v c3 = {r0.w, r1.w, r2.w, r3.w};
      *(short4v*)&Vt[db + 0][kb] = c0;
      *(short4v*)&Vt[db + 1][kb] = c1;
      *(short4v*)&Vt[db + 2][kb] = c2;
      *(short4v*)&Vt[db + 3][kb] = c3;
    }
    __syncthreads();

    // S^T = K * Q^T : rows k (frag kb), cols q
    f32x4 st[4];
#pragma unroll
    for (int kb = 0; kb < 4; ++kb) {
      f32x4 z = {0.f, 0.f, 0.f, 0.f};
      int row = kb * 16 + fr;
      int sw = row & 7;
      bf16x8 kf0 = *(const bf16x8*)&Ks[row][((fg) ^ sw) << 3];
      bf16x8 kf1 = *(const bf16x8*)&Ks[row][((4 + fg) ^ sw) << 3];
      z = __builtin_amdgcn_mfma_f32_16x16x32_bf16(kf0, qf[0], z, 0, 0, 0);
      z = __builtin_amdgcn_mfma_f32_16x16x32_bf16(kf1, qf[1], z, 0, 0, 0);
      st[kb] = z;
    }

    // online softmax over k (this lane's 16 values are for q = qcol)
    float p[16];
    float pmax = -3.0e38f;
#pragma unroll
    for (int kb = 0; kb < 4; ++kb)
#pragma unroll
      for (int r = 0; r < 4; ++r) {
        float s = st[kb][r] * 0.03125f;  // 1/sqrt(D)=1/32
        if (kt == tq) {
          int kg = k0 + kb * 16 + fg * 4 + r;
          if (kg < qcol) s = -3.0e38f;  // keep only k >= q
        }
        p[kb * 4 + r] = s;
        pmax = fmaxf(pmax, s);
      }
    pmax = fmaxf(pmax, __shfl_xor(pmax, 16, 64));
    pmax = fmaxf(pmax, __shfl_xor(pmax, 32, 64));
    float mnew = fmaxf(mrow, pmax);
    float scl = __expf(mrow - mnew);
    float psum = 0.f;
#pragma unroll
    for (int i = 0; i < 16; ++i) {
      float e = __expf(p[i] - mnew);
      p[i] = e;
      psum += e;
    }
    psum += __shfl_xor(psum, 16, 64);
    psum += __shfl_xor(psum, 32, 64);
    lsum = lsum * scl + psum;
    mrow = mnew;
    // rescale O (O rows live at q = fg*4+r; fetch that q's scale from lane q)
#pragma unroll
    for (int r = 0; r < 4; ++r) {
      float so = __shfl(scl, fg * 4 + r, 64);
#pragma unroll
      for (int f = 0; f < 4; ++f) o[f][r] *= so;
    }
    // P -> bf16 -> per-wave LDS [q][k] (k = kb*16 + fg*4 + r contiguous in r)
#pragma unroll
    for (int kb = 0; kb < 4; ++kb) {
      short4v pw = {f2bf(p[kb * 4 + 0]), f2bf(p[kb * 4 + 1]),
                    f2bf(p[kb * 4 + 2]), f2bf(p[kb * 4 + 3])};
      *(short4v*)&Pl[w][fr][kb * 16 + fg * 4] = pw;
    }
    // PV: O[q][d] += P[q][k] V[k][d]  (same-wave LDS RAW: DS ops are in-order)
    bf16x8 pa0 = *(const bf16x8*)&Pl[w][fr][fg * 8];
    bf16x8 pa1 = *(const bf16x8*)&Pl[w][fr][32 + fg * 8];
#pragma unroll
    for (int f = 0; f < 4; ++f) {
      bf16x8 v0 = *(const bf16x8*)&Vt[f * 16 + fr][fg * 8];
      bf16x8 v1 = *(const bf16x8*)&Vt[f * 16 + fr][32 + fg * 8];
      o[f] = __builtin_amdgcn_mfma_f32_16x16x32_bf16(pa0, v0, o[f], 0, 0, 0);
      o[f] = __builtin_amdgcn_mfma_f32_16x16x32_bf16(pa1, v1, o[f], 0, 0, 0);
    }
    __syncthreads();
  }

  // normalize + store bf16
#pragma unroll
  for (int r = 0; r < 4; ++r) {
    float denom = __shfl(lsum, fg * 4 + r, 64);
    float inv = 1.0f / denom;
    size_t orow = rowbase + (size_t)(q0 + w * 16 + fg * 4 + r);
    short* op = outc + orow * 1024 + h * 64 + fr;
#pragma unroll
    for (int f = 0; f < 4; ++f) op[f * 16] = f2bf(o[f][r] * inv);
  }
}

extern "C" void kernel_launch(void* const* d_in, const int* in_sizes, int n_in,
                              void* d_out, int out_size, void* d_ws,
                              size_t ws_size, hipStream_t stream) {
  const float* x = (const float*)d_in[0];
  const float* Wc = (const float*)d_in[1];
  const float* bc = (const float*)d_in[2];
  const float* Wo = (const float*)d_in[3];
  const float* bo = (const float*)d_in[4];
  float* out = (float*)d_out;

  const int Bn = 8, S = 1024, D = 1024;
  const int M = Bn * S;  // 8192

  char* ws = (char*)d_ws;
  short* xb  = (short*)(ws);                               // 16 MB
  short* wct = (short*)(ws + (size_t)16 * 1024 * 1024);    // 6 MB  [3072][1024]
  short* wot = (short*)(ws + (size_t)22 * 1024 * 1024);    // 2 MB  [1024][1024]
  short* qkv = (short*)(ws + (size_t)24 * 1024 * 1024);    // 48 MB [8192][3072]
  short* cat = (short*)(ws + (size_t)72 * 1024 * 1024);    // 16 MB [8192][1024]

  k_f32_to_bf16<<<(M * D / 4 + 255) / 256, 256, 0, stream>>>(x, xb, M * D / 4);
  {
    dim3 g(3 * D / 64, D / 64);
    k_transpose_bf16<<<g, 256, 0, stream>>>(Wc, wct, D, 3 * D);
  }
  {
    dim3 g(D / 64, D / 64);
    k_transpose_bf16<<<g, 256, 0, stream>>>(Wo, wot, D, D);
  }
  k_gemm_bt<false><<<(M / 128) * (3 * D / 128), 256, 0, stream>>>(
      xb, wct, bc, qkv, M, 3 * D, D);
  k_attn<<<Bn * 16 * 16, 256, 0, stream>>>(qkv, cat, Bn, S);
  k_gemm_bt<true><<<(M / 128) * (D / 128), 256, 0, stream>>>(
      cat, wot, bo, out, M, D, D);
}